// Round 7
// baseline (10346.230 us; speedup 1.0000x reference)
//
#include <hip/hip_runtime.h>
#include <hip/hip_bf16.h>
#include <stdint.h>

#define B_SZ 2048
#define H_SZ 1024
#define S_SZ 128
#define G4   4096
#define BK   32
#define NKK  32            // K phases per step
#define BM   128
#define BN   128
#define NJT  32            // G4/BN
#define NBLK 512

typedef short short8 __attribute__((ext_vector_type(8)));
typedef float floatx4 __attribute__((ext_vector_type(4)));

#define AS1 __attribute__((address_space(1)))
#define AS3 __attribute__((address_space(3)))

// Persistent device buffers (fully rewritten/reset on every kernel_launch).
// All global layouts LINEAR. LDS tiles use a chunk-major layout
// (elem = chunk*1024 + row*8 + e) chosen via per-lane gload source
// addresses -> uniform bank coverage on ds_read_b128, no swizzle anywhere.
__device__ ushort g_Wp[G4 * H_SZ];       // packed W_hh bf16: row j=(h/16)*64+gate*16+(h%16)
__device__ ushort g_h[2][B_SZ * H_SZ];   // hidden bf16 ping-pong
__device__ float  g_wih[G4];             // packed W_ih
__device__ float  g_bias[G4];            // packed b_ih + b_hh
__device__ float  g_pp[2][B_SZ][NJT];    // pred partials: [t&1][row][jt] (contig gather)
__device__ unsigned g_leaf[8 * 32];      // barrier leaves (1/XCD, 128B apart)
__device__ unsigned g_root;
__device__ unsigned g_gen;

__device__ __forceinline__ ushort f2bf(float f) {
  unsigned u = __float_as_uint(f);
  return (ushort)((u + 0x7FFFu + ((u >> 16) & 1u)) >> 16);
}
__device__ __forceinline__ float fsig(float x) { return 1.f / (1.f + __expf(-x)); }
__device__ __forceinline__ float ftanh(float x) { return 1.f - 2.f / (__expf(2.f * x) + 1.f); }

__device__ __forceinline__ void gload16(const void* g, void* l) {
  __builtin_amdgcn_global_load_lds((const AS1 void*)g, (AS3 void*)l, 16, 0, 0);
}

// Two-level grid barrier (8 leaves of 64 blocks, then root of 8).
// Entry __syncthreads drains each wave's vmcnt (stores complete in L2);
// tid0's release fence writes back dirty L2, acquire fence invalidates
// stale L1/L2 before any wave proceeds. Proven in round 6.
__device__ __forceinline__ void grid_barrier(int grp) {
  __syncthreads();
  if (threadIdx.x == 0) {
    __threadfence();
    unsigned gen = __hip_atomic_load(&g_gen, __ATOMIC_RELAXED, __HIP_MEMORY_SCOPE_AGENT);
    unsigned a = __hip_atomic_fetch_add(&g_leaf[grp * 32], 1u, __ATOMIC_ACQ_REL,
                                        __HIP_MEMORY_SCOPE_AGENT);
    if (a == 63u) {
      __hip_atomic_store(&g_leaf[grp * 32], 0u, __ATOMIC_RELAXED, __HIP_MEMORY_SCOPE_AGENT);
      unsigned r = __hip_atomic_fetch_add(&g_root, 1u, __ATOMIC_ACQ_REL,
                                          __HIP_MEMORY_SCOPE_AGENT);
      if (r == 7u) {
        __hip_atomic_store(&g_root, 0u, __ATOMIC_RELAXED, __HIP_MEMORY_SCOPE_AGENT);
        __hip_atomic_store(&g_gen, gen + 1u, __ATOMIC_RELEASE, __HIP_MEMORY_SCOPE_AGENT);
      } else {
        while (__hip_atomic_load(&g_gen, __ATOMIC_RELAXED, __HIP_MEMORY_SCOPE_AGENT) == gen)
          __builtin_amdgcn_s_sleep(2);
      }
    } else {
      while (__hip_atomic_load(&g_gen, __ATOMIC_RELAXED, __HIP_MEMORY_SCOPE_AGENT) == gen)
        __builtin_amdgcn_s_sleep(2);
    }
    __threadfence();
  }
  __syncthreads();
}

// ---------------- prep kernels ----------------

__global__ __launch_bounds__(256) void prep_wpack(const float* __restrict__ Whh) {
  const int gid = blockIdx.x * 256 + threadIdx.x;  // 524288
  const int j   = gid >> 7;
  const int k8  = (gid & 127) << 3;
  const int gate = (j >> 4) & 3;
  const int h    = ((j >> 6) << 4) | (j & 15);
  const float* src = Whh + (size_t)(gate * H_SZ + h) * H_SZ + k8;
  floatx4 a = *(const floatx4*)src;
  floatx4 b = *(const floatx4*)(src + 4);
  short8 o;
#pragma unroll
  for (int i = 0; i < 4; ++i) o[i] = (short)f2bf(a[i]);
#pragma unroll
  for (int i = 0; i < 4; ++i) o[4 + i] = (short)f2bf(b[i]);
  *(short8*)&g_Wp[(size_t)j * H_SZ + k8] = o;
}

__global__ __launch_bounds__(256) void prep_misc(const float* __restrict__ Wih,
                                                 const float* __restrict__ bih,
                                                 const float* __restrict__ bhh) {
  if (blockIdx.x == 0) {  // reset barrier state every call (determinism)
    if (threadIdx.x == 0) { g_root = 0u; g_gen = 0u; }
    if (threadIdx.x < 8) g_leaf[threadIdx.x * 32] = 0u;
  }
  const int j = blockIdx.x * 256 + threadIdx.x;  // 4096
  const int gate = (j >> 4) & 3;
  const int h    = ((j >> 6) << 4) | (j & 15);
  const int jp   = gate * H_SZ + h;
  g_wih[j]  = Wih[jp];
  g_bias[j] = bih[jp] + bhh[jp];
}

__global__ __launch_bounds__(256) void prep_h(const float* __restrict__ hidden) {
  const int gid = blockIdx.x * 256 + threadIdx.x;  // 262144
  const int o8  = gid << 3;
  short8 o;
#pragma unroll
  for (int i = 0; i < 8; ++i) o[i] = (short)f2bf(hidden[o8 + i]);
  *(short8*)&g_h[0][o8] = o;
}

// ---------------- persistent all-steps kernel ----------------
// 512 blocks x 256 threads, 2 blocks/CU (LDS 66KB -> co-resident by
// construction). XCD x = bid&7 owns 8 jt x 8 bt (W 2MB + h 2MB per L2).
// K-loop: 4-buffer ring, depth-3 prefetch, counted vmcnt + raw s_barrier.
__global__ __launch_bounds__(256, 2)
void lstm_persistent(const float* __restrict__ cell,
                     const float* __restrict__ Wfc,
                     const float* __restrict__ bfc,
                     float* __restrict__ out) {
  __shared__ ushort Al[4][BM * BK];   // 4 x 8KB
  __shared__ ushort Bl[4][BN * BK];   // 4 x 8KB
  __shared__ float  xbuf[BM];
  __shared__ float  predp[2 * BM];

  const int tid  = threadIdx.x;
  const int lane = tid & 63;
  const int wid  = tid >> 6;                     // 0..3
  const int bid  = blockIdx.x;
  const int grp  = bid & 7;                      // XCD (hw round-robin)
  const int idx  = bid >> 3;                     // 0..63
  const int jt   = (grp & 3) * 8 + (idx & 7);    // 0..31
  const int bt   = (grp >> 2) * 8 + (idx >> 3);  // 0..15
  const int brow = bt * BM;
  const int jcol = jt * BN;
  const int wr = wid >> 1, wc = wid & 1;
  const int lr = lane & 15, lk = lane >> 4;

  // staging: thread stages slots {tid, tid+256} of A and of B per phase.
  // slot s: chunk = s>>7 (0..3, = 8-elem K-group), row = s&127.
  // LDS dest is linear (slot*16B); global source encodes the chunk-major map.
  const int s0 = tid, s1 = tid + 256;
  const size_t aA0 = (size_t)(brow + (s0 & 127)) * H_SZ + ((s0 >> 7) << 3);
  const size_t aA1 = (size_t)(brow + (s1 & 127)) * H_SZ + ((s1 >> 7) << 3);
  const size_t aB0 = (size_t)(jcol + (s0 & 127)) * H_SZ + ((s0 >> 7) << 3);
  const size_t aB1 = (size_t)(jcol + (s1 & 127)) * H_SZ + ((s1 >> 7) << 3);

  // ds_read offsets: elem = lk*1024 + row*8
  int aoff[4], boff[4];
#pragma unroll
  for (int m = 0; m < 4; ++m) aoff[m] = lk * 1024 + (wr * 64 + m * 16 + lr) * 8;
#pragma unroll
  for (int n = 0; n < 4; ++n) boff[n] = lk * 1024 + (wc * 64 + n * 16 + lr) * 8;

  // hoisted epilogue constants
  const int hcol = (jt * 2 + wc) * 16 + lr;      // global h index 0..1023
  float wih[4], bb[4];
#pragma unroll
  for (int n = 0; n < 4; ++n) {
    const int col = jcol + wc * 64 + n * 16 + lr;
    wih[n] = g_wih[col];
    bb[n]  = g_bias[col];
  }

  // cell state in registers for the whole sequence
  float creg[4][4];
#pragma unroll
  for (int m = 0; m < 4; ++m)
#pragma unroll
    for (int r = 0; r < 4; ++r) {
      const int row_l = wr * 64 + m * 16 + lk * 4 + r;
      creg[m][r] = cell[(size_t)(brow + row_l) * H_SZ + hcol];
    }

#define STAGE(BUF, KO)                                                      \
  {                                                                         \
    const int ko_ = (KO) * BK;                                              \
    gload16(hin + aA0 + ko_, &Al[BUF][wid * 512]);                          \
    gload16(hin + aA1 + ko_, &Al[BUF][2048 + wid * 512]);                   \
    gload16(g_Wp + aB0 + ko_, &Bl[BUF][wid * 512]);                         \
    gload16(g_Wp + aB1 + ko_, &Bl[BUF][2048 + wid * 512]);                  \
  }

#define COMPUTE(BUF)                                                        \
  {                                                                         \
    const ushort* Ab = &Al[BUF][0];                                         \
    const ushort* Bb = &Bl[BUF][0];                                         \
    short8 a[4], b[4];                                                      \
    _Pragma("unroll") for (int m = 0; m < 4; ++m)                           \
        a[m] = *(const short8*)&Ab[aoff[m]];                                \
    _Pragma("unroll") for (int n = 0; n < 4; ++n)                           \
        b[n] = *(const short8*)&Bb[boff[n]];                                \
    __builtin_amdgcn_s_setprio(1);                                          \
    _Pragma("unroll") for (int m = 0; m < 4; ++m)                           \
        _Pragma("unroll") for (int n = 0; n < 4; ++n)                       \
            acc[m][n] = __builtin_amdgcn_mfma_f32_16x16x32_bf16(            \
                a[m], b[n], acc[m][n], 0, 0, 0);                            \
    __builtin_amdgcn_s_setprio(0);                                          \
  }

// Phase I: wait own phase-I loads (leave VN in flight), publish via barrier,
// prefetch phase I+3 (overwrites buf (I-1)&3 -- safe: all reads of it
// completed before this barrier), then compute phase I.
#define PHASE(I, VN)                                                        \
  {                                                                         \
    asm volatile("s_waitcnt vmcnt(" #VN ")" ::: "memory");                  \
    __builtin_amdgcn_sched_barrier(0);                                      \
    __builtin_amdgcn_s_barrier();                                           \
    if ((I) + 3 < NKK) { STAGE(((I) + 3) & 3, (I) + 3); }                   \
    COMPUTE((I) & 3);                                                       \
  }

  for (int t = 0; t < S_SZ; ++t) {
    const int p = t & 1;
    const ushort* __restrict__ hin = g_h[p];
    ushort* __restrict__ hout      = g_h[p ^ 1];

    floatx4 acc[4][4];
#pragma unroll
    for (int m = 0; m < 4; ++m)
#pragma unroll
      for (int n = 0; n < 4; ++n) acc[m][n] = {0.f, 0.f, 0.f, 0.f};

    // prologue: fill depth-3 pipeline (vmcnt = 12)
    STAGE(0, 0);
    STAGE(1, 1);
    STAGE(2, 2);

    for (int kq = 0; kq < 7; ++kq) {
      const int kk = kq * 4;
      PHASE(kk + 0, 8);
      PHASE(kk + 1, 8);
      PHASE(kk + 2, 8);
      PHASE(kk + 3, 8);
    }
    PHASE(28, 8);
    PHASE(29, 8);
    PHASE(30, 4);
    PHASE(31, 0);

    // ---------------- epilogue ----------------
    if (t > 0 && tid < BM) {
      const float* pr = &g_pp[(t - 1) & 1][brow + tid][0];
      float s = bfc[t - 1];
#pragma unroll
      for (int j = 0; j < 8; ++j) {
        floatx4 v = *(const floatx4*)&pr[j * 4];
        s += v[0] + v[1] + v[2] + v[3];
      }
      xbuf[tid] = s;
      if (jt == 0) out[(size_t)(brow + tid) * S_SZ + (t - 1)] = s;
    }
    __syncthreads();

    const float wfc_l = Wfc[(size_t)t * H_SZ + hcol];  // own-step head weight

#pragma unroll
    for (int m = 0; m < 4; ++m) {
#pragma unroll
      for (int r = 0; r < 4; ++r) {
        const int row_l = wr * 64 + m * 16 + lk * 4 + r;
        const float xv = (t > 0) ? xbuf[row_l] : 0.f;
        float gi = acc[m][0][r] + xv * wih[0] + bb[0];
        float gf = acc[m][1][r] + xv * wih[1] + bb[1];
        float gg = acc[m][2][r] + xv * wih[2] + bb[2];
        float go = acc[m][3][r] + xv * wih[3] + bb[3];
        float cn = fsig(gf) * creg[m][r] + fsig(gi) * ftanh(gg);
        creg[m][r] = cn;
        float hv = fsig(go) * ftanh(cn);
        hout[(size_t)(brow + row_l) * H_SZ + hcol] = f2bf(hv);
        // own-step head partial: pred_t[row] += h_t[row,hcol]*Wfc[t,hcol]
        float pp = hv * wfc_l;
        pp += __shfl_xor(pp, 1);
        pp += __shfl_xor(pp, 2);
        pp += __shfl_xor(pp, 4);
        pp += __shfl_xor(pp, 8);
        if (lr == 0) predp[wc * BM + row_l] = pp;
      }
    }
    __syncthreads();
    if (tid < BM)
      g_pp[p][brow + tid][jt] = predp[tid] + predp[BM + tid];

    grid_barrier(grp);
  }

  // final head output for t = S-1 (127 odd -> partials in g_pp[1])
  if (jt == 0 && tid < BM) {
    const float* pr = &g_pp[1][brow + tid][0];
    float s = bfc[S_SZ - 1];
#pragma unroll
    for (int j = 0; j < 8; ++j) {
      floatx4 v = *(const floatx4*)&pr[j * 4];
      s += v[0] + v[1] + v[2] + v[3];
    }
    out[(size_t)(brow + tid) * S_SZ + (S_SZ - 1)] = s;
  }
#undef STAGE
#undef COMPUTE
#undef PHASE
}

extern "C" void kernel_launch(void* const* d_in, const int* in_sizes, int n_in,
                              void* d_out, int out_size, void* d_ws, size_t ws_size,
                              hipStream_t stream) {
  const float* hidden = (const float*)d_in[0];
  const float* cell   = (const float*)d_in[1];
  const float* W_ih   = (const float*)d_in[2];
  const float* W_hh   = (const float*)d_in[3];
  const float* b_ih   = (const float*)d_in[4];
  const float* b_hh   = (const float*)d_in[5];
  const float* W_fc   = (const float*)d_in[6];
  const float* b_fc   = (const float*)d_in[7];
  float* out = (float*)d_out;

  prep_wpack<<<2048, 256, 0, stream>>>(W_hh);
  prep_misc<<<16, 256, 0, stream>>>(W_ih, b_ih, b_hh);
  prep_h<<<1024, 256, 0, stream>>>(hidden);

  lstm_persistent<<<NBLK, 256, 0, stream>>>(cell, W_fc, b_fc, out);
}

// Round 8
// 5737.145 us; speedup vs baseline: 1.8034x; 1.8034x over previous
//
#include <hip/hip_runtime.h>
#include <hip/hip_bf16.h>
#include <stdint.h>

#define B_SZ 2048
#define H_SZ 1024
#define S_SZ 128
#define G4   4096
#define BK   64
#define NKK  16            // K phases per step
#define BM   128
#define BN   256
#define NJT  16            // G4/BN
#define NBLK 256

typedef short short8 __attribute__((ext_vector_type(8)));
typedef int   intx4  __attribute__((ext_vector_type(4)));
typedef float floatx4 __attribute__((ext_vector_type(4)));

#define AS1 __attribute__((address_space(1)))
#define AS3 __attribute__((address_space(3)))

// Persistent device buffers (fully rewritten/reset on every kernel_launch).
// g_Wp is stored CHUNK-MAJOR per (jt,kt) tile:
//   g_Wp[jt*262144 + kt*16384 + c*2048 + r*8 + e], c=(k>>3)&7, r=row in panel.
// -> global_load_lds staging is fully linear/coalesced AND the LDS tile is
// chunk-major (conflict-free ds_read_b128). h stays row-major; its LDS
// transpose happens in the ds_write of the reg-staged path.
__device__ ushort g_Wp[G4 * H_SZ];
__device__ ushort g_h[2][B_SZ * H_SZ];   // hidden bf16 ping-pong, row-major
__device__ float  g_wih[G4];             // packed W_ih
__device__ float  g_bias[G4];            // packed b_ih + b_hh
__device__ float  g_pp[2][B_SZ][NJT];    // pred partials [t&1][row][jt]
__device__ unsigned g_leaf[8 * 32];      // barrier leaves (1/XCD, 128B apart)
__device__ unsigned g_root;
__device__ unsigned g_gen;

__device__ __forceinline__ ushort f2bf(float f) {
  unsigned u = __float_as_uint(f);
  return (ushort)((u + 0x7FFFu + ((u >> 16) & 1u)) >> 16);
}
__device__ __forceinline__ float fsig(float x) { return 1.f / (1.f + __expf(-x)); }
__device__ __forceinline__ float ftanh(float x) { return 1.f - 2.f / (__expf(2.f * x) + 1.f); }

__device__ __forceinline__ void gload16(const void* g, void* l) {
  __builtin_amdgcn_global_load_lds((const AS1 void*)g, (AS3 void*)l, 16, 0, 0);
}

// RELEASE-ONLY grid barrier: relaxed agent atomics + release fence (wbL2,
// NO L2 invalidate -> W stays warm in each XCD's L2 across all 128 steps).
// Cross-XCD reads (h, g_pp) never consult L2: h via sc0/sc1-bypass loads,
// g_pp via agent-scope atomic loads. Barrier vars are agent atomics (LLC).
__device__ __forceinline__ void grid_barrier(int grp) {
  __syncthreads();
  if (threadIdx.x == 0) {
    __builtin_amdgcn_fence(__ATOMIC_RELEASE, "agent");  // writeback dirty L2
    unsigned gen = __hip_atomic_load(&g_gen, __ATOMIC_RELAXED, __HIP_MEMORY_SCOPE_AGENT);
    unsigned a = __hip_atomic_fetch_add(&g_leaf[grp * 32], 1u, __ATOMIC_RELAXED,
                                        __HIP_MEMORY_SCOPE_AGENT);
    if (a == 31u) {
      __hip_atomic_store(&g_leaf[grp * 32], 0u, __ATOMIC_RELAXED, __HIP_MEMORY_SCOPE_AGENT);
      unsigned r = __hip_atomic_fetch_add(&g_root, 1u, __ATOMIC_RELAXED,
                                          __HIP_MEMORY_SCOPE_AGENT);
      if (r == 7u) {
        __hip_atomic_store(&g_root, 0u, __ATOMIC_RELAXED, __HIP_MEMORY_SCOPE_AGENT);
        __hip_atomic_store(&g_gen, gen + 1u, __ATOMIC_RELAXED, __HIP_MEMORY_SCOPE_AGENT);
      } else {
        while (__hip_atomic_load(&g_gen, __ATOMIC_RELAXED, __HIP_MEMORY_SCOPE_AGENT) == gen)
          __builtin_amdgcn_s_sleep(2);
      }
    } else {
      while (__hip_atomic_load(&g_gen, __ATOMIC_RELAXED, __HIP_MEMORY_SCOPE_AGENT) == gen)
        __builtin_amdgcn_s_sleep(2);
    }
    asm volatile("" ::: "memory");
  }
  __syncthreads();
}

// ---------------- prep kernels ----------------

__global__ __launch_bounds__(256) void prep_wpack(const float* __restrict__ Whh) {
  const int gid = blockIdx.x * 256 + threadIdx.x;  // 524288
  const int j   = gid >> 7;                        // packed row 0..4095
  const int k8  = (gid & 127) << 3;                // k offset 0..1016
  const int gate = (j >> 4) & 3;
  const int h    = ((j >> 6) << 4) | (j & 15);
  const float* src = Whh + (size_t)(gate * H_SZ + h) * H_SZ + k8;
  floatx4 a = *(const floatx4*)src;
  floatx4 b = *(const floatx4*)(src + 4);
  short8 o;
#pragma unroll
  for (int i = 0; i < 4; ++i) o[i] = (short)f2bf(a[i]);
#pragma unroll
  for (int i = 0; i < 4; ++i) o[4 + i] = (short)f2bf(b[i]);
  // chunk-major tile layout
  const size_t dst = (size_t)(j >> 8) * 262144 + (size_t)(k8 >> 6) * 16384 +
                     (size_t)((k8 >> 3) & 7) * 2048 + (size_t)(j & 255) * 8;
  *(short8*)&g_Wp[dst] = o;
}

__global__ __launch_bounds__(256) void prep_misc(const float* __restrict__ Wih,
                                                 const float* __restrict__ bih,
                                                 const float* __restrict__ bhh) {
  if (blockIdx.x == 0) {  // reset barrier state every call (determinism)
    if (threadIdx.x == 0) { g_root = 0u; g_gen = 0u; }
    if (threadIdx.x < 8) g_leaf[threadIdx.x * 32] = 0u;
  }
  const int j = blockIdx.x * 256 + threadIdx.x;  // 4096
  const int gate = (j >> 4) & 3;
  const int h    = ((j >> 6) << 4) | (j & 15);
  const int jp   = gate * H_SZ + h;
  g_wih[j]  = Wih[jp];
  g_bias[j] = bih[jp] + bhh[jp];
}

__global__ __launch_bounds__(256) void prep_h(const float* __restrict__ hidden) {
  const int gid = blockIdx.x * 256 + threadIdx.x;  // 262144
  const int o8  = gid << 3;
  short8 o;
#pragma unroll
  for (int i = 0; i < 8; ++i) o[i] = (short)f2bf(hidden[o8 + i]);
  *(short8*)&g_h[0][o8] = o;
}

// ---------------- persistent all-steps kernel ----------------
// 256 blocks x 512 threads (1 block/CU, 8 waves). XCD x = bid&7 owns
// jt in {2x, 2x+1} (W panels = 1MB, L2-resident for all steps) and all bt.
__global__ __launch_bounds__(512, 1)
void lstm_persistent(const float* __restrict__ cell,
                     const float* __restrict__ Wfc,
                     const float* __restrict__ bfc,
                     float* __restrict__ out) {
  __shared__ ushort Al[2][8256];    // A dbuf, chunk stride 1032 (pad: 2-way)
  __shared__ ushort Bl[3][16384];   // B ring-3, chunk stride 2048
  __shared__ float  xbuf[BM];
  __shared__ float  predp[4 * BM];

  const int tid  = threadIdx.x;
  const int lane = tid & 63;
  const int wid  = tid >> 6;                  // 0..7
  const int bid  = blockIdx.x;
  const int grp  = bid & 7;                   // XCD (hw round-robin)
  const int idx  = bid >> 3;                  // 0..31
  const int jt   = (grp << 1) | (idx & 1);    // 0..15 (2 W panels per XCD)
  const int bt   = idx >> 1;                  // 0..15
  const int brow = bt * BM;
  const int wr = wid >> 2, wc = wid & 3;      // wave tile 2 x 4
  const int lr = lane & 15, lk = lane >> 4;

  const size_t wbase = (size_t)jt * 262144;
  // A reg-staging: thread covers h[brow + (tid>>2)][(tid&3)*16 .. +16) per tile
  const size_t abase = (size_t)(brow + (tid >> 2)) * H_SZ + (size_t)(tid & 3) * 16;
  ushort* const awp = &Al[0][((tid & 3) * 2) * 1032 + (tid >> 2) * 8];

  // hoisted epilogue constants
  const int hcol = ((jt << 2) + wc) * 16 + lr;  // global h index 0..1023
  float wih[4], bb[4];
#pragma unroll
  for (int n = 0; n < 4; ++n) {
    const int col = jt * BN + wc * 64 + n * 16 + lr;
    wih[n] = g_wih[col];
    bb[n]  = g_bias[col];
  }

  // cell state in registers for the whole sequence
  float creg[4][4];
#pragma unroll
  for (int m = 0; m < 4; ++m)
#pragma unroll
    for (int r = 0; r < 4; ++r) {
      const int row_l = wr * 64 + m * 16 + lk * 4 + r;
      creg[m][r] = cell[(size_t)(brow + row_l) * H_SZ + hcol];
    }

  intx4 a0, a1, a2, a3;  // A reg-staging double buffer (2 x 32B)

#define ISSUE_B(I)                                                          \
  {                                                                         \
    const ushort* bs = g_Wp + wbase + (size_t)(I) * 16384 + (size_t)tid * 8;\
    ushort* bd = &Bl[(I) % 3][(tid & 448) * 8];                             \
    gload16(bs, bd);                                                        \
    gload16(bs + 4096, bd + 4096);                                          \
    gload16(bs + 8192, bd + 8192);                                          \
    gload16(bs + 12288, bd + 12288);                                        \
  }

#define ISSUE_A(I, AW0, AW1)                                                \
  {                                                                         \
    const ushort* as_ = hin + abase + (size_t)(I) * 64;                     \
    asm volatile("global_load_dwordx4 %0, %1, off sc0 sc1"                  \
                 : "=v"(AW0) : "v"(as_));                                   \
    asm volatile("global_load_dwordx4 %0, %1, off sc0 sc1"                  \
                 : "=v"(AW1) : "v"(as_ + 8));                               \
  }

#define COMPUTE(BA, BB)                                                     \
  {                                                                         \
    _Pragma("unroll") for (int k2 = 0; k2 < 2; ++k2) {                      \
      const int co = k2 * 4 + lk;                                           \
      short8 a[4], b[4];                                                    \
      _Pragma("unroll") for (int m = 0; m < 4; ++m)                         \
          a[m] = *(const short8*)&Al[BA][co * 1032 + (wr * 64 + m * 16 + lr) * 8]; \
      _Pragma("unroll") for (int n = 0; n < 4; ++n)                         \
          b[n] = *(const short8*)&Bl[BB][co * 2048 + (wc * 64 + n * 16 + lr) * 8]; \
      __builtin_amdgcn_s_setprio(1);                                        \
      _Pragma("unroll") for (int m = 0; m < 4; ++m)                         \
          _Pragma("unroll") for (int n = 0; n < 4; ++n)                     \
              acc[m][n] = __builtin_amdgcn_mfma_f32_16x16x32_bf16(          \
                  a[m], b[n], acc[m][n], 0, 0, 0);                          \
      __builtin_amdgcn_s_setprio(0);                                        \
    }                                                                       \
  }

// Phase I (I<15): issue tile I+1, wait own tile-I loads (6 newest stay in
// flight), transpose-write A(I) to LDS, publish, compute tile I.
#define PH(I, AW0, AW1, AR0, AR1)                                           \
  {                                                                         \
    ISSUE_B((I) + 1);                                                       \
    ISSUE_A((I) + 1, AW0, AW1);                                             \
    asm volatile("s_waitcnt vmcnt(6)" ::: "memory");                        \
    __builtin_amdgcn_sched_barrier(0);                                      \
    *(intx4*)(awp + ((I) & 1) * 8256) = AR0;                                \
    *(intx4*)(awp + ((I) & 1) * 8256 + 1032) = AR1;                         \
    asm volatile("s_waitcnt lgkmcnt(0)" ::: "memory");                      \
    __builtin_amdgcn_s_barrier();                                           \
    __builtin_amdgcn_sched_barrier(0);                                      \
    COMPUTE((I) & 1, (I) % 3);                                              \
  }

#define PHLAST                                                              \
  {                                                                         \
    asm volatile("s_waitcnt vmcnt(0)" ::: "memory");                        \
    __builtin_amdgcn_sched_barrier(0);                                      \
    *(intx4*)(awp + 8256) = a2;                                             \
    *(intx4*)(awp + 8256 + 1032) = a3;                                      \
    asm volatile("s_waitcnt lgkmcnt(0)" ::: "memory");                      \
    __builtin_amdgcn_s_barrier();                                           \
    __builtin_amdgcn_sched_barrier(0);                                      \
    COMPUTE(1, 0);                                                          \
  }

  for (int t = 0; t < S_SZ; ++t) {
    const int p = t & 1;
    const ushort* __restrict__ hin = g_h[p];
    ushort* __restrict__ hout      = g_h[p ^ 1];

    floatx4 acc[4][4];
#pragma unroll
    for (int m = 0; m < 4; ++m)
#pragma unroll
      for (int n = 0; n < 4; ++n) acc[m][n] = {0.f, 0.f, 0.f, 0.f};

    // prologue: issue tile 0
    ISSUE_B(0);
    ISSUE_A(0, a0, a1);

    PH(0,  a2, a3, a0, a1);
    PH(1,  a0, a1, a2, a3);
    PH(2,  a2, a3, a0, a1);
    PH(3,  a0, a1, a2, a3);
    PH(4,  a2, a3, a0, a1);
    PH(5,  a0, a1, a2, a3);
    PH(6,  a2, a3, a0, a1);
    PH(7,  a0, a1, a2, a3);
    PH(8,  a2, a3, a0, a1);
    PH(9,  a0, a1, a2, a3);
    PH(10, a2, a3, a0, a1);
    PH(11, a0, a1, a2, a3);
    PH(12, a2, a3, a0, a1);
    PH(13, a0, a1, a2, a3);
    PH(14, a2, a3, a0, a1);
    PHLAST;

    // ---------------- epilogue ----------------
    if (t > 0 && tid < BM) {
      float s = bfc[t - 1];
      const float* pr = &g_pp[(t - 1) & 1][brow + tid][0];
#pragma unroll
      for (int j = 0; j < NJT; ++j)
        s += __hip_atomic_load(pr + j, __ATOMIC_RELAXED, __HIP_MEMORY_SCOPE_AGENT);
      xbuf[tid] = s;
      if (jt == 0) out[(size_t)(brow + tid) * S_SZ + (t - 1)] = s;
    }
    __syncthreads();

    const float wfc_l = Wfc[(size_t)t * H_SZ + hcol];  // own-step head weight

#pragma unroll
    for (int m = 0; m < 4; ++m) {
#pragma unroll
      for (int r = 0; r < 4; ++r) {
        const int row_l = wr * 64 + m * 16 + lk * 4 + r;
        const float xv = (t > 0) ? xbuf[row_l] : 0.f;
        float gi = acc[m][0][r] + xv * wih[0] + bb[0];
        float gf = acc[m][1][r] + xv * wih[1] + bb[1];
        float gg = acc[m][2][r] + xv * wih[2] + bb[2];
        float go = acc[m][3][r] + xv * wih[3] + bb[3];
        float cn = fsig(gf) * creg[m][r] + fsig(gi) * ftanh(gg);
        creg[m][r] = cn;
        float hv = fsig(go) * ftanh(cn);
        hout[(size_t)(brow + row_l) * H_SZ + hcol] = f2bf(hv);
        float pp = hv * wfc_l;
        pp += __shfl_xor(pp, 1);
        pp += __shfl_xor(pp, 2);
        pp += __shfl_xor(pp, 4);
        pp += __shfl_xor(pp, 8);
        if (lr == 0) predp[wc * BM + row_l] = pp;
      }
    }
    __syncthreads();
    if (tid < BM)
      g_pp[p][brow + tid][jt] = predp[tid] + predp[BM + tid] +
                                predp[2 * BM + tid] + predp[3 * BM + tid];

    grid_barrier(grp);
  }

  // final head output for t = S-1 (127 odd -> partials in g_pp[1])
  if (jt == 0 && tid < BM) {
    float s = bfc[S_SZ - 1];
    const float* pr = &g_pp[1][brow + tid][0];
#pragma unroll
    for (int j = 0; j < NJT; ++j)
      s += __hip_atomic_load(pr + j, __ATOMIC_RELAXED, __HIP_MEMORY_SCOPE_AGENT);
    out[(size_t)(brow + tid) * S_SZ + (S_SZ - 1)] = s;
  }
#undef ISSUE_B
#undef ISSUE_A
#undef COMPUTE
#undef PH
#undef PHLAST
}

extern "C" void kernel_launch(void* const* d_in, const int* in_sizes, int n_in,
                              void* d_out, int out_size, void* d_ws, size_t ws_size,
                              hipStream_t stream) {
  const float* hidden = (const float*)d_in[0];
  const float* cell   = (const float*)d_in[1];
  const float* W_ih   = (const float*)d_in[2];
  const float* W_hh   = (const float*)d_in[3];
  const float* b_ih   = (const float*)d_in[4];
  const float* b_hh   = (const float*)d_in[5];
  const float* W_fc   = (const float*)d_in[6];
  const float* b_fc   = (const float*)d_in[7];
  float* out = (float*)d_out;

  prep_wpack<<<2048, 256, 0, stream>>>(W_hh);
  prep_misc<<<16, 256, 0, stream>>>(W_ih, b_ih, b_hh);
  prep_h<<<1024, 256, 0, stream>>>(hidden);

  lstm_persistent<<<NBLK, 512, 0, stream>>>(cell, W_fc, b_fc, out);
}